// Round 5
// baseline (237.317 us; speedup 1.0000x reference)
//
#include <hip/hip_runtime.h>
#include <hip/hip_bf16.h>
#include <cstdint>

typedef __bf16 bf16x8 __attribute__((ext_vector_type(8)));
typedef float f32x4 __attribute__((ext_vector_type(4)));
typedef uint4 __attribute__((may_alias)) uint4a;

typedef __attribute__((address_space(3))) unsigned int   lds_u32;
typedef __attribute__((address_space(1))) const unsigned int gbl_u32;

#define BATCH 4
#define SEQ   2048
#define CDIM  1024
#define NH    16
#define HD    64

#define C1SCALE 0.18033688011112042f  /* Dh^-0.5 * log2(e), folded into Q */

__device__ __forceinline__ unsigned short f2bf(float f) {
    uint32_t u = __builtin_bit_cast(uint32_t, f);
    u += 0x7fffu + ((u >> 16) & 1u);
    return (unsigned short)(u >> 16);
}

#if __has_builtin(__builtin_amdgcn_cvt_pk_bf16_f32)
typedef __bf16 bf16x2 __attribute__((ext_vector_type(2)));
__device__ __forceinline__ uint32_t pk2bf(float a, float b) {
    bf16x2 v = __builtin_amdgcn_cvt_pk_bf16_f32(a, b);
    return __builtin_bit_cast(uint32_t, v);
}
#else
__device__ __forceinline__ uint32_t pk2bf(float a, float b) {
    return (uint32_t)f2bf(a) | ((uint32_t)f2bf(b) << 16);
}
#endif

// async 16B/lane global->LDS (wave-uniform LDS base; HW writes base+lane*16)
__device__ __forceinline__ void g2l16(const unsigned short* g, unsigned short* l) {
    __builtin_amdgcn_global_load_lds((gbl_u32*)g, (lds_u32*)l, 16, 0, 0);
}

// ---------------- fused prep: cvt(x) + transpose(Wqkv) + transpose(Wproj)
// ---------------- + mask scan -> compacted row-index table ridx
#define NB_CVT   8192
#define NB_TQKV  3072
#define NB_TPROJ 1024
#define NB_PREP  (NB_CVT + NB_TQKV + NB_TPROJ + 4)

__global__ __launch_bounds__(256)
void prep_kernel(const float* __restrict__ x,
                 const float* __restrict__ Wqkv,
                 const float* __restrict__ Wproj,
                 const int* __restrict__ mask,
                 unsigned short* __restrict__ xb,
                 unsigned short* __restrict__ Wqkvt,
                 unsigned short* __restrict__ Wprojt,
                 int* __restrict__ ridx, int* __restrict__ cnt) {
    __shared__ float tile[32][33];
    __shared__ int s[256];
    int bid = blockIdx.x, tid = threadIdx.x;

    if (bid < NB_CVT) {
        int i = (bid * 256 + tid) * 4;
        float4 v = *(const float4*)(x + i);
        uint2 o;
        o.x = pk2bf(v.x, v.y);
        o.y = pk2bf(v.z, v.w);
        *(uint2*)(xb + i) = o;
        return;
    }
    if (bid < NB_CVT + NB_TQKV + NB_TPROJ) {
        const float* in;
        unsigned short* out;
        int Cc, bx;
        if (bid < NB_CVT + NB_TQKV) {
            bx = bid - NB_CVT; in = Wqkv; out = Wqkvt; Cc = 3072;
        } else {
            bx = bid - NB_CVT - NB_TQKV; in = Wproj; out = Wprojt; Cc = 1024;
        }
        int nbx = Cc >> 5;
        int c0 = (bx % nbx) * 32, r0 = (bx / nbx) * 32;
        int tx = tid & 31, ty = tid >> 5;
        #pragma unroll
        for (int i = 0; i < 32; i += 8)
            tile[ty + i][tx] = in[(size_t)(r0 + ty + i) * Cc + c0 + tx];
        __syncthreads();
        #pragma unroll
        for (int i = 0; i < 32; i += 8)
            out[(size_t)(c0 + ty + i) * 1024 + r0 + tx] = f2bf(tile[tx][ty + i]);
        return;
    }
    // per-batch mask compaction scan -> ridx[b][pos] = original n (kept rows),
    // tail slots zero-filled so gathers are always in-bounds
    int b = bid - (NB_CVT + NB_TQKV + NB_TPROJ);
    int keep[8], lc = 0;
    #pragma unroll
    for (int u = 0; u < 8; ++u) {
        keep[u] = (mask[b * SEQ + tid * 8 + u] > 0) ? 0 : 1;
        lc += keep[u];
    }
    s[tid] = lc;
    __syncthreads();
    for (int d = 1; d < 256; d <<= 1) {
        int w = (tid >= d) ? s[tid - d] : 0;
        __syncthreads();
        s[tid] += w;
        __syncthreads();
    }
    int pos = s[tid] - lc;
    #pragma unroll
    for (int u = 0; u < 8; ++u) {
        if (keep[u]) ridx[b * SEQ + pos++] = tid * 8 + u;
    }
    int total = s[255];
    for (int i = total + tid; i < SEQ; i += 256)
        ridx[b * SEQ + i] = 0;
    if (tid == 255) cnt[b] = total;
}

// ---------------- GEMM 1 (merged): Q-path + KV-path in one dispatch -------
// y<8:  Q = xb @ Wqkvt[:1024], pre-scaled, -> [B,H,N,Dh]
// y>=8: K,V = gather(xb,ridx) @ Wqkvt[1024:], compacted M, -> Kc / Vct
// m97-proven structure: 128x128 tile, BK=64, 16B-granule XOR swizzle.
#define BK 64

__global__ __launch_bounds__(256, 2)
void gemm_qkv2_kernel(const unsigned short* __restrict__ A,
                      const unsigned short* __restrict__ Bt,
                      const int* __restrict__ ridx,
                      const int* __restrict__ cnt,
                      unsigned short* __restrict__ Q,
                      unsigned short* __restrict__ Kc,
                      unsigned short* __restrict__ Vct) {
    __shared__ __align__(16) unsigned short sA[128 * 64];
    __shared__ __align__(16) unsigned short sB[128 * 64];
    const int Kdim = 1024;
    int tid = threadIdx.x;
    int wave = tid >> 6, lane = tid & 63;
    int wm = (wave >> 1) * 64, wn = (wave & 1) * 64;
    int l15 = lane & 15, quad = lane >> 4;
    int lr = lane >> 3, lc8 = ((lane & 7) ^ lr) * 8;  // swizzled source col

    const bool qpath = (blockIdx.y < 8);
    int m0, n0, b = 0, kn = 0;
    const unsigned short* aPtr[4];   // per-lane A source base (col k0=0)

    if (qpath) {
        m0 = blockIdx.x * 128;
        n0 = blockIdx.y * 128;
        #pragma unroll
        for (int it = 0; it < 4; ++it) {
            int gr = (wave * 4 + it) * 8 + lr;
            aPtr[it] = A + (size_t)(m0 + gr) * Kdim + lc8;
        }
    } else {
        b  = blockIdx.x >> 4;
        m0 = (blockIdx.x & 15) * 128;
        kn = cnt[b];
        if (m0 >= kn) return;             // block-uniform, before any barrier
        n0 = 1024 + (blockIdx.y - 8) * 128;
        #pragma unroll
        for (int it = 0; it < 4; ++it) {
            int gr = (wave * 4 + it) * 8 + lr;
            int rid = ridx[b * SEQ + m0 + gr];    // original n (0 for tail)
            aPtr[it] = A + (size_t)(b * SEQ + rid) * Kdim + lc8;
        }
    }

    f32x4 acc[4][4] = {};

    for (int k0 = 0; k0 < Kdim; k0 += BK) {
        #pragma unroll
        for (int it = 0; it < 4; ++it) {
            int c = wave * 4 + it;            // chunk: 8 rows x 64 cols
            int gr = c * 8 + lr;
            g2l16(aPtr[it] + k0, &sA[c * 512]);
            g2l16(Bt + (size_t)(n0 + gr) * Kdim + k0 + lc8, &sB[c * 512]);
        }
        __syncthreads();
        #pragma unroll
        for (int kk = 0; kk < BK; kk += 32) {
            bf16x8 af[4], bfr[4];
            #pragma unroll
            for (int i = 0; i < 4; ++i) {
                int r = wm + i * 16 + l15;
                int q = ((kk >> 3) + quad) ^ (r & 7);
                af[i] = __builtin_bit_cast(bf16x8, *(const uint4a*)(&sA[r * 64 + q * 8]));
            }
            #pragma unroll
            for (int j = 0; j < 4; ++j) {
                int r = wn + j * 16 + l15;
                int q = ((kk >> 3) + quad) ^ (r & 7);
                bfr[j] = __builtin_bit_cast(bf16x8, *(const uint4a*)(&sB[r * 64 + q * 8]));
            }
            #pragma unroll
            for (int i = 0; i < 4; ++i)
                #pragma unroll
                for (int j = 0; j < 4; ++j)
                    acc[i][j] = __builtin_amdgcn_mfma_f32_16x16x32_bf16(af[i], bfr[j], acc[i][j], 0, 0, 0);
        }
        __syncthreads();
    }

    if (qpath) {
        // Q pre-scaled by C1SCALE -> [B,H,N,Dh]
        #pragma unroll
        for (int i = 0; i < 4; ++i) {
            #pragma unroll
            for (int j = 0; j < 4; ++j) {
                int col = n0 + wn + j * 16 + l15;
                int h = col >> 6;
                int d = col & 63;
                int row0 = m0 + wm + i * 16 + quad * 4;
                int bb = row0 >> 11, n = row0 & 2047;
                size_t bh = (size_t)(bb * NH + h);
                uint32_t p01 = pk2bf(acc[i][j][0] * C1SCALE, acc[i][j][1] * C1SCALE);
                uint32_t p23 = pk2bf(acc[i][j][2] * C1SCALE, acc[i][j][3] * C1SCALE);
                size_t base = (bh * SEQ + n) * HD + d;
                Q[base]          = (unsigned short)p01;
                Q[base + HD]     = (unsigned short)(p01 >> 16);
                Q[base + 2 * HD] = (unsigned short)p23;
                Q[base + 3 * HD] = (unsigned short)(p23 >> 16);
            }
        }
    } else {
        // rows already compacted positions; guard tail rows
        #pragma unroll
        for (int i = 0; i < 4; ++i) {
            #pragma unroll
            for (int j = 0; j < 4; ++j) {
                int c2 = (n0 - 1024) + wn + j * 16 + l15;   // 0..2047
                int three = c2 >> 10;                        // 0=K, 1=V
                int h = (c2 >> 6) & 15;
                int d = c2 & 63;
                int pf0 = m0 + wm + i * 16 + quad * 4;
                size_t bh = (size_t)(b * NH + h);
                if (three == 0) {
                    #pragma unroll
                    for (int r = 0; r < 4; ++r) {
                        int pf = pf0 + r;
                        if (pf < kn) Kc[(bh * SEQ + pf) * HD + d] = f2bf(acc[i][j][r]);
                    }
                } else {
                    #pragma unroll
                    for (int r = 0; r < 4; ++r) {
                        int pf = pf0 + r;
                        if (pf < kn) Vct[(bh * HD + d) * SEQ + pf] = f2bf(acc[i][j][r]);
                    }
                }
            }
        }
    }
}

// ---------------- GEMM 2: out = attn @ Wproj + bias (fp32 out) ------------
__global__ __launch_bounds__(256, 2)
void gemm_proj_kernel(const unsigned short* __restrict__ A,
                      const unsigned short* __restrict__ Bt,
                      const float* __restrict__ bias,
                      float* __restrict__ Out) {
    __shared__ __align__(16) unsigned short sA[128 * 64];
    __shared__ __align__(16) unsigned short sB[128 * 64];
    const int Kdim = 1024;
    int m0 = blockIdx.x * 128;
    int n0 = blockIdx.y * 128;
    int tid = threadIdx.x;
    int wave = tid >> 6, lane = tid & 63;
    int wm = (wave >> 1) * 64, wn = (wave & 1) * 64;
    int l15 = lane & 15, quad = lane >> 4;
    int lr = lane >> 3, lc8 = ((lane & 7) ^ lr) * 8;

    f32x4 acc[4][4] = {};

    for (int k0 = 0; k0 < Kdim; k0 += BK) {
        #pragma unroll
        for (int it = 0; it < 4; ++it) {
            int c = wave * 4 + it;
            int gr = c * 8 + lr;
            g2l16(A  + (size_t)(m0 + gr) * Kdim + k0 + lc8, &sA[c * 512]);
            g2l16(Bt + (size_t)(n0 + gr) * Kdim + k0 + lc8, &sB[c * 512]);
        }
        __syncthreads();
        #pragma unroll
        for (int kk = 0; kk < BK; kk += 32) {
            bf16x8 af[4], bfr[4];
            #pragma unroll
            for (int i = 0; i < 4; ++i) {
                int r = wm + i * 16 + l15;
                int q = ((kk >> 3) + quad) ^ (r & 7);
                af[i] = __builtin_bit_cast(bf16x8, *(const uint4a*)(&sA[r * 64 + q * 8]));
            }
            #pragma unroll
            for (int j = 0; j < 4; ++j) {
                int r = wn + j * 16 + l15;
                int q = ((kk >> 3) + quad) ^ (r & 7);
                bfr[j] = __builtin_bit_cast(bf16x8, *(const uint4a*)(&sB[r * 64 + q * 8]));
            }
            #pragma unroll
            for (int i = 0; i < 4; ++i)
                #pragma unroll
                for (int j = 0; j < 4; ++j)
                    acc[i][j] = __builtin_amdgcn_mfma_f32_16x16x32_bf16(af[i], bfr[j], acc[i][j], 0, 0, 0);
        }
        __syncthreads();
    }

    #pragma unroll
    for (int i = 0; i < 4; ++i) {
        #pragma unroll
        for (int j = 0; j < 4; ++j) {
            int col = n0 + wn + j * 16 + l15;
            float bv = bias[col];
            #pragma unroll
            for (int r = 0; r < 4; ++r) {
                int row = m0 + wm + i * 16 + quad * 4 + r;
                Out[(size_t)row * CDIM + col] = acc[i][j][r] + bv;
            }
        }
    }
}

// ---------------- Flash attention v10 --------------------------------------
// v9 + T3 minimum 2-phase prefetch: double-buffered K/V staging issued at
// the TOP of each tile's compute, drained by the single end-of-tile
// __syncthreads (compiler vmcnt(0) there happens AFTER ~500cy of compute ->
// staging latency hidden). Barriers: 2 -> 1 per tile. LDS 50 KB -> 3
// blocks/CU (~= measured time-avg occupancy anyway).
#define SPD 72   /* sP row stride (shorts), 144B rows (16B aligned) */

__global__ __launch_bounds__(256, 3)
void flash_attn_kernel(const unsigned short* __restrict__ Q,
                       const unsigned short* __restrict__ Kg,
                       const unsigned short* __restrict__ Vt,
                       const int* __restrict__ cnt,
                       unsigned short* __restrict__ O) {
    int bh = blockIdx.x;
    int q0 = blockIdx.y * 128;
    int b = bh >> 4, h = bh & 15;
    int tid = threadIdx.x;
    int wave = tid >> 6, lane = tid & 63;
    int l15 = lane & 15, quad = lane >> 4;
    int lr = lane >> 3, lc8 = ((lane & 7) ^ lr) * 8;

    const int kn = cnt[b];

    const size_t head_off = (size_t)bh * SEQ * HD;
    const unsigned short* Qh = Q + head_off;
    const unsigned short* Kh = Kg + head_off;
    const unsigned short* Vh = Vt + head_off;   // [HD][SEQ]

    __shared__ __align__(16) unsigned short sK [2][64 * 64];
    __shared__ __align__(16) unsigned short sVt[2][64 * 64];
    __shared__ __align__(16) unsigned short sP [4][32 * SPD];  // per-wave, both mt

    bf16x8 qf[2][2];
    #pragma unroll
    for (int mt = 0; mt < 2; ++mt) {
        const unsigned short* qp = Qh + (size_t)(q0 + wave * 32 + mt * 16 + l15) * HD + quad * 8;
        qf[mt][0] = __builtin_bit_cast(bf16x8, *(const uint4a*)(qp));
        qf[mt][1] = __builtin_bit_cast(bf16x8, *(const uint4a*)(qp + 32));
    }

    bf16x8 ones;
    {
        uint4 ov;
        ov.x = ov.y = ov.z = ov.w = 0x3F803F80u;
        ones = __builtin_bit_cast(bf16x8, ov);
    }

    f32x4 oacc[2][4] = {};
    f32x4 oextra[2] = {};   // oextra[mt][r] = l[row] (ones-column MFMA)

    // stage one 64-col K/V tile into buffer p (4 async loads per wave)
    auto stage = [&](int k0, int p) {
        #pragma unroll
        for (int it = 0; it < 2; ++it) {
            int c = wave * 2 + it;
            int gr = c * 8 + lr;
            g2l16(Kh + (size_t)(k0 + gr) * HD + lc8, &sK[p][c * 512]);
            g2l16(Vh + (size_t)gr * SEQ + k0 + lc8, &sVt[p][c * 512]);
        }
    };

    stage(0, 0);
    __syncthreads();   // compiler emits vmcnt(0): buf0 ready

    for (int k0 = 0; k0 < kn; k0 += 64) {
        int p = (k0 >> 6) & 1;
        // prefetch next tile into the other buffer BEFORE compute; its loads
        // stay in flight until the end-of-tile barrier's vmcnt(0)
        if (k0 + 64 < kn) stage(k0 + 64, p ^ 1);

        bool tail = (k0 + 64 > kn);   // block-uniform

        // ---- S = Q K^T for BOTH mt halves; each kf pair read once ----
        f32x4 s[2][4] = {};
        #pragma unroll
        for (int j = 0; j < 4; ++j) {
            int r = j * 16 + l15, sw = r & 7;
            uint4 v0 = *(const uint4a*)(&sK[p][r * 64 + ((quad ^ sw) * 8)]);
            uint4 v1 = *(const uint4a*)(&sK[p][r * 64 + (((4 + quad) ^ sw) * 8)]);
            bf16x8 k0f = __builtin_bit_cast(bf16x8, v0);
            bf16x8 k1f = __builtin_bit_cast(bf16x8, v1);
            __builtin_amdgcn_s_setprio(1);
            s[0][j] = __builtin_amdgcn_mfma_f32_16x16x32_bf16(qf[0][0], k0f, s[0][j], 0, 0, 0);
            s[0][j] = __builtin_amdgcn_mfma_f32_16x16x32_bf16(qf[0][1], k1f, s[0][j], 0, 0, 0);
            s[1][j] = __builtin_amdgcn_mfma_f32_16x16x32_bf16(qf[1][0], k0f, s[1][j], 0, 0, 0);
            s[1][j] = __builtin_amdgcn_mfma_f32_16x16x32_bf16(qf[1][1], k1f, s[1][j], 0, 0, 0);
            __builtin_amdgcn_s_setprio(0);
        }

        // ---- softmax (exp2) + pack both halves into sP (32 rows) ----
        unsigned short* sp = &sP[wave][0];
        #pragma unroll
        for (int mt = 0; mt < 2; ++mt) {
            if (tail) {
                #pragma unroll
                for (int j = 0; j < 4; ++j) {
                    float madd = (k0 + j * 16 + l15 < kn) ? 0.f : -1e30f;
                    #pragma unroll
                    for (int r = 0; r < 4; ++r)
                        s[mt][j][r] = __builtin_amdgcn_exp2f(s[mt][j][r] + madd);
                }
            } else {
                #pragma unroll
                for (int j = 0; j < 4; ++j)
                    #pragma unroll
                    for (int r = 0; r < 4; ++r)
                        s[mt][j][r] = __builtin_amdgcn_exp2f(s[mt][j][r]);
            }
            #pragma unroll
            for (int j = 0; j < 4; ++j) {
                uint32_t p01 = pk2bf(s[mt][j][0], s[mt][j][1]);
                uint32_t p23 = pk2bf(s[mt][j][2], s[mt][j][3]);
                int base = (mt * 16 + quad * 4) * SPD + j * 16 + l15;
                sp[base]           = (unsigned short)p01;
                sp[base + SPD]     = (unsigned short)(p01 >> 16);
                sp[base + 2 * SPD] = (unsigned short)p23;
                sp[base + 3 * SPD] = (unsigned short)(p23 >> 16);
            }
        }

        // ---- O += P V for BOTH mt halves; each vf read once ----
        #pragma unroll
        for (int kc = 0; kc < 2; ++kc) {
            uint4 a0 = *(const uint4a*)(&sp[(l15)      * SPD + kc * 32 + quad * 8]);
            uint4 a1 = *(const uint4a*)(&sp[(16 + l15) * SPD + kc * 32 + quad * 8]);
            bf16x8 af0 = __builtin_bit_cast(bf16x8, a0);
            bf16x8 af1 = __builtin_bit_cast(bf16x8, a1);
            __builtin_amdgcn_s_setprio(1);
            #pragma unroll
            for (int jd = 0; jd < 4; ++jd) {
                int r = jd * 16 + l15;
                int q = ((kc * 4 + quad) ^ (r & 7)) * 8;
                uint4 bv = *(const uint4a*)(&sVt[p][r * 64 + q]);
                bf16x8 vf = __builtin_bit_cast(bf16x8, bv);
                oacc[0][jd] = __builtin_amdgcn_mfma_f32_16x16x32_bf16(af0, vf, oacc[0][jd], 0, 0, 0);
                oacc[1][jd] = __builtin_amdgcn_mfma_f32_16x16x32_bf16(af1, vf, oacc[1][jd], 0, 0, 0);
            }
            oextra[0] = __builtin_amdgcn_mfma_f32_16x16x32_bf16(af0, ones, oextra[0], 0, 0, 0);
            oextra[1] = __builtin_amdgcn_mfma_f32_16x16x32_bf16(af1, ones, oextra[1], 0, 0, 0);
            __builtin_amdgcn_s_setprio(0);
        }

        // single end-of-tile barrier: drains the prefetch (vmcnt(0)) and
        // protects buffer reuse for the next iteration
        __syncthreads();
    }

    // epilogue: O *= 1/l, write [B,N,C] bf16
    #pragma unroll
    for (int mt = 0; mt < 2; ++mt) {
        float rl[4];
        #pragma unroll
        for (int r = 0; r < 4; ++r) rl[r] = __builtin_amdgcn_rcpf(oextra[mt][r]);
        #pragma unroll
        for (int jd = 0; jd < 4; ++jd) {
            int d = jd * 16 + l15;
            size_t base = ((size_t)(b * SEQ + q0 + wave * 32 + mt * 16 + quad * 4)) * CDIM + h * HD + d;
            uint32_t p01 = pk2bf(oacc[mt][jd][0] * rl[0], oacc[mt][jd][1] * rl[1]);
            uint32_t p23 = pk2bf(oacc[mt][jd][2] * rl[2], oacc[mt][jd][3] * rl[3]);
            O[base]            = (unsigned short)p01;
            O[base + CDIM]     = (unsigned short)(p01 >> 16);
            O[base + 2 * CDIM] = (unsigned short)p23;
            O[base + 3 * CDIM] = (unsigned short)(p23 >> 16);
        }
    }
}

extern "C" void kernel_launch(void* const* d_in, const int* in_sizes, int n_in,
                              void* d_out, int out_size, void* d_ws, size_t ws_size,
                              hipStream_t stream) {
    const float* x     = (const float*)d_in[0];
    const float* Wqkv  = (const float*)d_in[1];
    const float* Wproj = (const float*)d_in[2];
    const float* bproj = (const float*)d_in[3];
    const int*   mask  = (const int*)d_in[4];
    float* out = (float*)d_out;

    char* ws = (char*)d_ws;
    unsigned short* xb     = (unsigned short*)(ws);                       // 16 MB (also attn out)
    unsigned short* Wqkvt  = (unsigned short*)(ws + (16u << 20));         // 6 MB
    unsigned short* Wprojt = (unsigned short*)(ws + (22u << 20));         // 2 MB
    unsigned short* Qb     = (unsigned short*)(ws + (24u << 20));         // 16 MB
    unsigned short* Kb     = (unsigned short*)(ws + (40u << 20));         // 16 MB
    unsigned short* Vtb    = (unsigned short*)(ws + (56u << 20));         // 16 MB, ends 72 MB
    int*            ridx   = (int*)(ws + (72u << 20));                    // 32 KB
    int*            cntb   = (int*)(ws + (72u << 20) + (32u << 10));      // 16 B

    prep_kernel<<<dim3(NB_PREP), dim3(256), 0, stream>>>(x, Wqkv, Wproj, mask,
                                                         xb, Wqkvt, Wprojt, ridx, cntb);
    gemm_qkv2_kernel<<<dim3(64, 24), dim3(256), 0, stream>>>(xb, Wqkvt, ridx, cntb, Qb, Kb, Vtb);
    flash_attn_kernel<<<dim3(64, 16), dim3(256), 0, stream>>>(Qb, Kb, Vtb, cntb, xb);
    gemm_proj_kernel<<<dim3(64, 8), dim3(256), 0, stream>>>(xb, Wprojt, bproj, out);
}

// Round 6
// 231.127 us; speedup vs baseline: 1.0268x; 1.0268x over previous
//
#include <hip/hip_runtime.h>
#include <hip/hip_bf16.h>
#include <cstdint>

typedef __bf16 bf16x8 __attribute__((ext_vector_type(8)));
typedef float f32x4 __attribute__((ext_vector_type(4)));
typedef uint4 __attribute__((may_alias)) uint4a;
typedef uint2 __attribute__((may_alias)) uint2a;

typedef __attribute__((address_space(3))) unsigned int   lds_u32;
typedef __attribute__((address_space(1))) const unsigned int gbl_u32;

#define BATCH 4
#define SEQ   2048
#define CDIM  1024
#define NH    16
#define HD    64

#define C1SCALE 0.18033688011112042f  /* Dh^-0.5 * log2(e), folded into Q */

__device__ __forceinline__ unsigned short f2bf(float f) {
    uint32_t u = __builtin_bit_cast(uint32_t, f);
    u += 0x7fffu + ((u >> 16) & 1u);
    return (unsigned short)(u >> 16);
}

#if __has_builtin(__builtin_amdgcn_cvt_pk_bf16_f32)
typedef __bf16 bf16x2 __attribute__((ext_vector_type(2)));
__device__ __forceinline__ uint32_t pk2bf(float a, float b) {
    bf16x2 v = __builtin_amdgcn_cvt_pk_bf16_f32(a, b);
    return __builtin_bit_cast(uint32_t, v);
}
#else
__device__ __forceinline__ uint32_t pk2bf(float a, float b) {
    return (uint32_t)f2bf(a) | ((uint32_t)f2bf(b) << 16);
}
#endif

// async 16B/lane global->LDS (wave-uniform LDS base; HW writes base+lane*16)
__device__ __forceinline__ void g2l16(const unsigned short* g, unsigned short* l) {
    __builtin_amdgcn_global_load_lds((gbl_u32*)g, (lds_u32*)l, 16, 0, 0);
}

// ---------------- fused prep: cvt(x) + transpose(Wqkv) + transpose(Wproj)
// ---------------- + mask scan -> compacted row-index table ridx
#define NB_CVT   8192
#define NB_TQKV  3072
#define NB_TPROJ 1024
#define NB_PREP  (NB_CVT + NB_TQKV + NB_TPROJ + 4)

__global__ __launch_bounds__(256)
void prep_kernel(const float* __restrict__ x,
                 const float* __restrict__ Wqkv,
                 const float* __restrict__ Wproj,
                 const int* __restrict__ mask,
                 unsigned short* __restrict__ xb,
                 unsigned short* __restrict__ Wqkvt,
                 unsigned short* __restrict__ Wprojt,
                 int* __restrict__ ridx, int* __restrict__ cnt) {
    __shared__ float tile[32][33];
    __shared__ int s[256];
    int bid = blockIdx.x, tid = threadIdx.x;

    if (bid < NB_CVT) {
        int i = (bid * 256 + tid) * 4;
        float4 v = *(const float4*)(x + i);
        uint2 o;
        o.x = pk2bf(v.x, v.y);
        o.y = pk2bf(v.z, v.w);
        *(uint2*)(xb + i) = o;
        return;
    }
    if (bid < NB_CVT + NB_TQKV + NB_TPROJ) {
        const float* in;
        unsigned short* out;
        int Cc, bx;
        if (bid < NB_CVT + NB_TQKV) {
            bx = bid - NB_CVT; in = Wqkv; out = Wqkvt; Cc = 3072;
        } else {
            bx = bid - NB_CVT - NB_TQKV; in = Wproj; out = Wprojt; Cc = 1024;
        }
        int nbx = Cc >> 5;
        int c0 = (bx % nbx) * 32, r0 = (bx / nbx) * 32;
        int tx = tid & 31, ty = tid >> 5;
        #pragma unroll
        for (int i = 0; i < 32; i += 8)
            tile[ty + i][tx] = in[(size_t)(r0 + ty + i) * Cc + c0 + tx];
        __syncthreads();
        #pragma unroll
        for (int i = 0; i < 32; i += 8)
            out[(size_t)(c0 + ty + i) * 1024 + r0 + tx] = f2bf(tile[tx][ty + i]);
        return;
    }
    // per-batch mask compaction scan -> ridx[b][pos] = original n (kept rows),
    // tail slots zero-filled so gathers are always in-bounds
    int b = bid - (NB_CVT + NB_TQKV + NB_TPROJ);
    int keep[8], lc = 0;
    #pragma unroll
    for (int u = 0; u < 8; ++u) {
        keep[u] = (mask[b * SEQ + tid * 8 + u] > 0) ? 0 : 1;
        lc += keep[u];
    }
    s[tid] = lc;
    __syncthreads();
    for (int d = 1; d < 256; d <<= 1) {
        int w = (tid >= d) ? s[tid - d] : 0;
        __syncthreads();
        s[tid] += w;
        __syncthreads();
    }
    int pos = s[tid] - lc;
    #pragma unroll
    for (int u = 0; u < 8; ++u) {
        if (keep[u]) ridx[b * SEQ + pos++] = tid * 8 + u;
    }
    int total = s[255];
    for (int i = total + tid; i < SEQ; i += 256)
        ridx[b * SEQ + i] = 0;
    if (tid == 255) cnt[b] = total;
}

// ---------------- GEMM 1 (merged): Q-path + KV-path in one dispatch -------
// y<8:  Q = xb @ Wqkvt[:1024], pre-scaled, -> [B,H,N,Dh]
// y>=8: K,V = gather(xb,ridx) @ Wqkvt[1024:], compacted M, -> Kc / Vct
// m97-proven structure: 128x128 tile, BK=64, 16B-granule XOR swizzle.
#define BK 64

__global__ __launch_bounds__(256, 2)
void gemm_qkv2_kernel(const unsigned short* __restrict__ A,
                      const unsigned short* __restrict__ Bt,
                      const int* __restrict__ ridx,
                      const int* __restrict__ cnt,
                      unsigned short* __restrict__ Q,
                      unsigned short* __restrict__ Kc,
                      unsigned short* __restrict__ Vct) {
    __shared__ __align__(16) unsigned short sA[128 * 64];
    __shared__ __align__(16) unsigned short sB[128 * 64];
    const int Kdim = 1024;
    int tid = threadIdx.x;
    int wave = tid >> 6, lane = tid & 63;
    int wm = (wave >> 1) * 64, wn = (wave & 1) * 64;
    int l15 = lane & 15, quad = lane >> 4;
    int lr = lane >> 3, lc8 = ((lane & 7) ^ lr) * 8;  // swizzled source col

    const bool qpath = (blockIdx.y < 8);
    int m0, n0, b = 0, kn = 0;
    const unsigned short* aPtr[4];   // per-lane A source base (col k0=0)

    if (qpath) {
        m0 = blockIdx.x * 128;
        n0 = blockIdx.y * 128;
        #pragma unroll
        for (int it = 0; it < 4; ++it) {
            int gr = (wave * 4 + it) * 8 + lr;
            aPtr[it] = A + (size_t)(m0 + gr) * Kdim + lc8;
        }
    } else {
        b  = blockIdx.x >> 4;
        m0 = (blockIdx.x & 15) * 128;
        kn = cnt[b];
        if (m0 >= kn) return;             // block-uniform, before any barrier
        n0 = 1024 + (blockIdx.y - 8) * 128;
        #pragma unroll
        for (int it = 0; it < 4; ++it) {
            int gr = (wave * 4 + it) * 8 + lr;
            int rid = ridx[b * SEQ + m0 + gr];    // original n (0 for tail)
            aPtr[it] = A + (size_t)(b * SEQ + rid) * Kdim + lc8;
        }
    }

    f32x4 acc[4][4] = {};

    for (int k0 = 0; k0 < Kdim; k0 += BK) {
        #pragma unroll
        for (int it = 0; it < 4; ++it) {
            int c = wave * 4 + it;            // chunk: 8 rows x 64 cols
            int gr = c * 8 + lr;
            g2l16(aPtr[it] + k0, &sA[c * 512]);
            g2l16(Bt + (size_t)(n0 + gr) * Kdim + k0 + lc8, &sB[c * 512]);
        }
        __syncthreads();
        #pragma unroll
        for (int kk = 0; kk < BK; kk += 32) {
            bf16x8 af[4], bfr[4];
            #pragma unroll
            for (int i = 0; i < 4; ++i) {
                int r = wm + i * 16 + l15;
                int q = ((kk >> 3) + quad) ^ (r & 7);
                af[i] = __builtin_bit_cast(bf16x8, *(const uint4a*)(&sA[r * 64 + q * 8]));
            }
            #pragma unroll
            for (int j = 0; j < 4; ++j) {
                int r = wn + j * 16 + l15;
                int q = ((kk >> 3) + quad) ^ (r & 7);
                bfr[j] = __builtin_bit_cast(bf16x8, *(const uint4a*)(&sB[r * 64 + q * 8]));
            }
            #pragma unroll
            for (int i = 0; i < 4; ++i)
                #pragma unroll
                for (int j = 0; j < 4; ++j)
                    acc[i][j] = __builtin_amdgcn_mfma_f32_16x16x32_bf16(af[i], bfr[j], acc[i][j], 0, 0, 0);
        }
        __syncthreads();
    }

    if (qpath) {
        // Q pre-scaled by C1SCALE -> [B,H,N,Dh]
        #pragma unroll
        for (int i = 0; i < 4; ++i) {
            #pragma unroll
            for (int j = 0; j < 4; ++j) {
                int col = n0 + wn + j * 16 + l15;
                int h = col >> 6;
                int d = col & 63;
                int row0 = m0 + wm + i * 16 + quad * 4;
                int bb = row0 >> 11, n = row0 & 2047;
                size_t bh = (size_t)(bb * NH + h);
                uint32_t p01 = pk2bf(acc[i][j][0] * C1SCALE, acc[i][j][1] * C1SCALE);
                uint32_t p23 = pk2bf(acc[i][j][2] * C1SCALE, acc[i][j][3] * C1SCALE);
                size_t base = (bh * SEQ + n) * HD + d;
                Q[base]          = (unsigned short)p01;
                Q[base + HD]     = (unsigned short)(p01 >> 16);
                Q[base + 2 * HD] = (unsigned short)p23;
                Q[base + 3 * HD] = (unsigned short)(p23 >> 16);
            }
        }
    } else {
        // rows already compacted positions; guard tail rows
        #pragma unroll
        for (int i = 0; i < 4; ++i) {
            #pragma unroll
            for (int j = 0; j < 4; ++j) {
                int c2 = (n0 - 1024) + wn + j * 16 + l15;   // 0..2047
                int three = c2 >> 10;                        // 0=K, 1=V
                int h = (c2 >> 6) & 15;
                int d = c2 & 63;
                int pf0 = m0 + wm + i * 16 + quad * 4;
                size_t bh = (size_t)(b * NH + h);
                if (three == 0) {
                    #pragma unroll
                    for (int r = 0; r < 4; ++r) {
                        int pf = pf0 + r;
                        if (pf < kn) Kc[(bh * SEQ + pf) * HD + d] = f2bf(acc[i][j][r]);
                    }
                } else {
                    #pragma unroll
                    for (int r = 0; r < 4; ++r) {
                        int pf = pf0 + r;
                        if (pf < kn) Vct[(bh * HD + d) * SEQ + pf] = f2bf(acc[i][j][r]);
                    }
                }
            }
        }
    }
}

// ---------------- GEMM 2: out = attn @ Wproj + bias (fp32 out) ------------
__global__ __launch_bounds__(256, 2)
void gemm_proj_kernel(const unsigned short* __restrict__ A,
                      const unsigned short* __restrict__ Bt,
                      const float* __restrict__ bias,
                      float* __restrict__ Out) {
    __shared__ __align__(16) unsigned short sA[128 * 64];
    __shared__ __align__(16) unsigned short sB[128 * 64];
    const int Kdim = 1024;
    int m0 = blockIdx.x * 128;
    int n0 = blockIdx.y * 128;
    int tid = threadIdx.x;
    int wave = tid >> 6, lane = tid & 63;
    int wm = (wave >> 1) * 64, wn = (wave & 1) * 64;
    int l15 = lane & 15, quad = lane >> 4;
    int lr = lane >> 3, lc8 = ((lane & 7) ^ lr) * 8;

    f32x4 acc[4][4] = {};

    for (int k0 = 0; k0 < Kdim; k0 += BK) {
        #pragma unroll
        for (int it = 0; it < 4; ++it) {
            int c = wave * 4 + it;
            int gr = c * 8 + lr;
            g2l16(A  + (size_t)(m0 + gr) * Kdim + k0 + lc8, &sA[c * 512]);
            g2l16(Bt + (size_t)(n0 + gr) * Kdim + k0 + lc8, &sB[c * 512]);
        }
        __syncthreads();
        #pragma unroll
        for (int kk = 0; kk < BK; kk += 32) {
            bf16x8 af[4], bfr[4];
            #pragma unroll
            for (int i = 0; i < 4; ++i) {
                int r = wm + i * 16 + l15;
                int q = ((kk >> 3) + quad) ^ (r & 7);
                af[i] = __builtin_bit_cast(bf16x8, *(const uint4a*)(&sA[r * 64 + q * 8]));
            }
            #pragma unroll
            for (int j = 0; j < 4; ++j) {
                int r = wn + j * 16 + l15;
                int q = ((kk >> 3) + quad) ^ (r & 7);
                bfr[j] = __builtin_bit_cast(bf16x8, *(const uint4a*)(&sB[r * 64 + q * 8]));
            }
            #pragma unroll
            for (int i = 0; i < 4; ++i)
                #pragma unroll
                for (int j = 0; j < 4; ++j)
                    acc[i][j] = __builtin_amdgcn_mfma_f32_16x16x32_bf16(af[i], bfr[j], acc[i][j], 0, 0, 0);
        }
        __syncthreads();
    }

    #pragma unroll
    for (int i = 0; i < 4; ++i) {
        #pragma unroll
        for (int j = 0; j < 4; ++j) {
            int col = n0 + wn + j * 16 + l15;
            float bv = bias[col];
            #pragma unroll
            for (int r = 0; r < 4; ++r) {
                int row = m0 + wm + i * 16 + quad * 4 + r;
                Out[(size_t)row * CDIM + col] = acc[i][j][r] + bv;
            }
        }
    }
}

// ---------------- Flash attention v11 --------------------------------------
// v9 structure (single-buffer K/V staging, 4 blocks/CU) + SWAPPED QK^T:
// S^T = mfma(K, Q) puts q in D-cols (l15) and k in D-rows (quad*4+r+16j),
// so each lane's 4 P-values per j are k-ADJACENT -> pack with pk2bf and
// store with ONE ds_write_b64 per (mt,j): 8 b64 writes replace 32 b16
// writes per wave-tile. PV read addressing identical to v9 (rows = q = l15).
// A/B fragments have identical per-lane layouts for 16x16x32, so the same
// kf/qf register fragments serve the swapped MFMA unchanged.
#define SPD 72   /* sP row stride (shorts), 144B rows (16B aligned) */

__global__ __launch_bounds__(256, 4)
void flash_attn_kernel(const unsigned short* __restrict__ Q,
                       const unsigned short* __restrict__ Kg,
                       const unsigned short* __restrict__ Vt,
                       const int* __restrict__ cnt,
                       unsigned short* __restrict__ O) {
    int bh = blockIdx.x;
    int q0 = blockIdx.y * 128;
    int b = bh >> 4, h = bh & 15;
    int tid = threadIdx.x;
    int wave = tid >> 6, lane = tid & 63;
    int l15 = lane & 15, quad = lane >> 4;
    int lr = lane >> 3, lc8 = ((lane & 7) ^ lr) * 8;

    const int kn = cnt[b];

    const size_t head_off = (size_t)bh * SEQ * HD;
    const unsigned short* Qh = Q + head_off;
    const unsigned short* Kh = Kg + head_off;
    const unsigned short* Vh = Vt + head_off;   // [HD][SEQ]

    __shared__ __align__(16) unsigned short sK [64 * 64];
    __shared__ __align__(16) unsigned short sVt[64 * 64];
    __shared__ __align__(16) unsigned short sP [4][32 * SPD];  // per-wave P^T-packed [q][k]

    bf16x8 qf[2][2];
    #pragma unroll
    for (int mt = 0; mt < 2; ++mt) {
        const unsigned short* qp = Qh + (size_t)(q0 + wave * 32 + mt * 16 + l15) * HD + quad * 8;
        qf[mt][0] = __builtin_bit_cast(bf16x8, *(const uint4a*)(qp));
        qf[mt][1] = __builtin_bit_cast(bf16x8, *(const uint4a*)(qp + 32));
    }

    bf16x8 ones;
    {
        uint4 ov;
        ov.x = ov.y = ov.z = ov.w = 0x3F803F80u;
        ones = __builtin_bit_cast(bf16x8, ov);
    }

    f32x4 oacc[2][4] = {};
    f32x4 oextra[2] = {};   // oextra[mt][r] = l[row] (ones-column MFMA)

    for (int k0 = 0; k0 < kn; k0 += 64) {
        #pragma unroll
        for (int it = 0; it < 2; ++it) {
            int c = wave * 2 + it;
            int gr = c * 8 + lr;
            g2l16(Kh + (size_t)(k0 + gr) * HD + lc8, &sK[c * 512]);
            g2l16(Vh + (size_t)gr * SEQ + k0 + lc8, &sVt[c * 512]);
        }
        __syncthreads();

        bool tail = (k0 + 64 > kn);   // block-uniform

        // ---- S^T = K Q^T for BOTH mt halves; each kf pair read once ----
        // s[mt][j][r] = P[q = mt*16+l15][k = j*16 + quad*4 + r]  (pre-exp)
        f32x4 s[2][4] = {};
        #pragma unroll
        for (int j = 0; j < 4; ++j) {
            int r = j * 16 + l15, sw = r & 7;
            uint4 v0 = *(const uint4a*)(&sK[r * 64 + ((quad ^ sw) * 8)]);
            uint4 v1 = *(const uint4a*)(&sK[r * 64 + (((4 + quad) ^ sw) * 8)]);
            bf16x8 k0f = __builtin_bit_cast(bf16x8, v0);
            bf16x8 k1f = __builtin_bit_cast(bf16x8, v1);
            __builtin_amdgcn_s_setprio(1);
            s[0][j] = __builtin_amdgcn_mfma_f32_16x16x32_bf16(k0f, qf[0][0], s[0][j], 0, 0, 0);
            s[0][j] = __builtin_amdgcn_mfma_f32_16x16x32_bf16(k1f, qf[0][1], s[0][j], 0, 0, 0);
            s[1][j] = __builtin_amdgcn_mfma_f32_16x16x32_bf16(k0f, qf[1][0], s[1][j], 0, 0, 0);
            s[1][j] = __builtin_amdgcn_mfma_f32_16x16x32_bf16(k1f, qf[1][1], s[1][j], 0, 0, 0);
            __builtin_amdgcn_s_setprio(0);
        }

        // ---- softmax (exp2) + pack: one b64 write per (mt,j) ----
        unsigned short* sp = &sP[wave][0];
        #pragma unroll
        for (int mt = 0; mt < 2; ++mt) {
            int row = mt * 16 + l15;
            #pragma unroll
            for (int j = 0; j < 4; ++j) {
                if (tail) {
                    int kb = k0 + j * 16 + quad * 4;
                    #pragma unroll
                    for (int r = 0; r < 4; ++r)
                        s[mt][j][r] = __builtin_amdgcn_exp2f(s[mt][j][r] + ((kb + r < kn) ? 0.f : -1e30f));
                } else {
                    #pragma unroll
                    for (int r = 0; r < 4; ++r)
                        s[mt][j][r] = __builtin_amdgcn_exp2f(s[mt][j][r]);
                }
                uint2 wv;
                wv.x = pk2bf(s[mt][j][0], s[mt][j][1]);
                wv.y = pk2bf(s[mt][j][2], s[mt][j][3]);
                *(uint2a*)(&sp[row * SPD + j * 16 + quad * 4]) = wv;
            }
        }

        // ---- O += P V for BOTH mt halves; each vf read once ----
        #pragma unroll
        for (int kc = 0; kc < 2; ++kc) {
            uint4 a0 = *(const uint4a*)(&sp[(l15)      * SPD + kc * 32 + quad * 8]);
            uint4 a1 = *(const uint4a*)(&sp[(16 + l15) * SPD + kc * 32 + quad * 8]);
            bf16x8 af0 = __builtin_bit_cast(bf16x8, a0);
            bf16x8 af1 = __builtin_bit_cast(bf16x8, a1);
            __builtin_amdgcn_s_setprio(1);
            #pragma unroll
            for (int jd = 0; jd < 4; ++jd) {
                int r = jd * 16 + l15;
                int q = ((kc * 4 + quad) ^ (r & 7)) * 8;
                uint4 bv = *(const uint4a*)(&sVt[r * 64 + q]);
                bf16x8 vf = __builtin_bit_cast(bf16x8, bv);
                oacc[0][jd] = __builtin_amdgcn_mfma_f32_16x16x32_bf16(af0, vf, oacc[0][jd], 0, 0, 0);
                oacc[1][jd] = __builtin_amdgcn_mfma_f32_16x16x32_bf16(af1, vf, oacc[1][jd], 0, 0, 0);
            }
            oextra[0] = __builtin_amdgcn_mfma_f32_16x16x32_bf16(af0, ones, oextra[0], 0, 0, 0);
            oextra[1] = __builtin_amdgcn_mfma_f32_16x16x32_bf16(af1, ones, oextra[1], 0, 0, 0);
            __builtin_amdgcn_s_setprio(0);
        }
        __syncthreads();
    }

    // epilogue: O *= 1/l, write [B,N,C] bf16  (oacc/oextra layouts unchanged)
    #pragma unroll
    for (int mt = 0; mt < 2; ++mt) {
        float rl[4];
        #pragma unroll
        for (int r = 0; r < 4; ++r) rl[r] = __builtin_amdgcn_rcpf(oextra[mt][r]);
        #pragma unroll
        for (int jd = 0; jd < 4; ++jd) {
            int d = jd * 16 + l15;
            size_t base = ((size_t)(b * SEQ + q0 + wave * 32 + mt * 16 + quad * 4)) * CDIM + h * HD + d;
            uint32_t p01 = pk2bf(oacc[mt][jd][0] * rl[0], oacc[mt][jd][1] * rl[1]);
            uint32_t p23 = pk2bf(oacc[mt][jd][2] * rl[2], oacc[mt][jd][3] * rl[3]);
            O[base]            = (unsigned short)p01;
            O[base + CDIM]     = (unsigned short)(p01 >> 16);
            O[base + 2 * CDIM] = (unsigned short)p23;
            O[base + 3 * CDIM] = (unsigned short)(p23 >> 16);
        }
    }
}

extern "C" void kernel_launch(void* const* d_in, const int* in_sizes, int n_in,
                              void* d_out, int out_size, void* d_ws, size_t ws_size,
                              hipStream_t stream) {
    const float* x     = (const float*)d_in[0];
    const float* Wqkv  = (const float*)d_in[1];
    const float* Wproj = (const float*)d_in[2];
    const float* bproj = (const float*)d_in[3];
    const int*   mask  = (const int*)d_in[4];
    float* out = (float*)d_out;

    char* ws = (char*)d_ws;
    unsigned short* xb     = (unsigned short*)(ws);                       // 16 MB (also attn out)
    unsigned short* Wqkvt  = (unsigned short*)(ws + (16u << 20));         // 6 MB
    unsigned short* Wprojt = (unsigned short*)(ws + (22u << 20));         // 2 MB
    unsigned short* Qb     = (unsigned short*)(ws + (24u << 20));         // 16 MB
    unsigned short* Kb     = (unsigned short*)(ws + (40u << 20));         // 16 MB
    unsigned short* Vtb    = (unsigned short*)(ws + (56u << 20));         // 16 MB, ends 72 MB
    int*            ridx   = (int*)(ws + (72u << 20));                    // 32 KB
    int*            cntb   = (int*)(ws + (72u << 20) + (32u << 10));      // 16 B

    prep_kernel<<<dim3(NB_PREP), dim3(256), 0, stream>>>(x, Wqkv, Wproj, mask,
                                                         xb, Wqkvt, Wprojt, ridx, cntb);
    gemm_qkv2_kernel<<<dim3(64, 24), dim3(256), 0, stream>>>(xb, Wqkvt, ridx, cntb, Qb, Kb, Vtb);
    flash_attn_kernel<<<dim3(64, 16), dim3(256), 0, stream>>>(Qb, Kb, Vtb, cntb, xb);
    gemm_proj_kernel<<<dim3(64, 8), dim3(256), 0, stream>>>(xb, Wprojt, bproj, out);
}

// Round 7
// 225.294 us; speedup vs baseline: 1.0534x; 1.0259x over previous
//
#include <hip/hip_runtime.h>
#include <hip/hip_bf16.h>
#include <cstdint>

typedef __bf16 bf16x8 __attribute__((ext_vector_type(8)));
typedef float f32x4 __attribute__((ext_vector_type(4)));
typedef uint4 __attribute__((may_alias)) uint4a;
typedef uint2 __attribute__((may_alias)) uint2a;

typedef __attribute__((address_space(3))) unsigned int   lds_u32;
typedef __attribute__((address_space(1))) const unsigned int gbl_u32;

#define BATCH 4
#define SEQ   2048
#define CDIM  1024
#define NH    16
#define HD    64

#define C1SCALE 0.18033688011112042f  /* Dh^-0.5 * log2(e), folded into Q */

__device__ __forceinline__ unsigned short f2bf(float f) {
    uint32_t u = __builtin_bit_cast(uint32_t, f);
    u += 0x7fffu + ((u >> 16) & 1u);
    return (unsigned short)(u >> 16);
}

#if __has_builtin(__builtin_amdgcn_cvt_pk_bf16_f32)
typedef __bf16 bf16x2 __attribute__((ext_vector_type(2)));
__device__ __forceinline__ uint32_t pk2bf(float a, float b) {
    bf16x2 v = __builtin_amdgcn_cvt_pk_bf16_f32(a, b);
    return __builtin_bit_cast(uint32_t, v);
}
#else
__device__ __forceinline__ uint32_t pk2bf(float a, float b) {
    return (uint32_t)f2bf(a) | ((uint32_t)f2bf(b) << 16);
}
#endif

// async 16B/lane global->LDS (wave-uniform LDS base; HW writes base+lane*16)
__device__ __forceinline__ void g2l16(const unsigned short* g, unsigned short* l) {
    __builtin_amdgcn_global_load_lds((gbl_u32*)g, (lds_u32*)l, 16, 0, 0);
}

// ---------------- fused prep: cvt(x) + transpose(Wqkv) + transpose(Wproj)
// ---------------- + mask scan -> compacted row-index table ridx
#define NB_CVT   8192
#define NB_TQKV  3072
#define NB_TPROJ 1024
#define NB_PREP  (NB_CVT + NB_TQKV + NB_TPROJ + 4)

__global__ __launch_bounds__(256)
void prep_kernel(const float* __restrict__ x,
                 const float* __restrict__ Wqkv,
                 const float* __restrict__ Wproj,
                 const int* __restrict__ mask,
                 unsigned short* __restrict__ xb,
                 unsigned short* __restrict__ Wqkvt,
                 unsigned short* __restrict__ Wprojt,
                 int* __restrict__ ridx, int* __restrict__ cnt) {
    __shared__ float tile[32][33];
    __shared__ int s[256];
    int bid = blockIdx.x, tid = threadIdx.x;

    if (bid < NB_CVT) {
        int i = (bid * 256 + tid) * 4;
        float4 v = *(const float4*)(x + i);
        uint2 o;
        o.x = pk2bf(v.x, v.y);
        o.y = pk2bf(v.z, v.w);
        *(uint2*)(xb + i) = o;
        return;
    }
    if (bid < NB_CVT + NB_TQKV + NB_TPROJ) {
        const float* in;
        unsigned short* out;
        int Cc, bx;
        if (bid < NB_CVT + NB_TQKV) {
            bx = bid - NB_CVT; in = Wqkv; out = Wqkvt; Cc = 3072;
        } else {
            bx = bid - NB_CVT - NB_TQKV; in = Wproj; out = Wprojt; Cc = 1024;
        }
        int nbx = Cc >> 5;
        int c0 = (bx % nbx) * 32, r0 = (bx / nbx) * 32;
        int tx = tid & 31, ty = tid >> 5;
        #pragma unroll
        for (int i = 0; i < 32; i += 8)
            tile[ty + i][tx] = in[(size_t)(r0 + ty + i) * Cc + c0 + tx];
        __syncthreads();
        #pragma unroll
        for (int i = 0; i < 32; i += 8)
            out[(size_t)(c0 + ty + i) * 1024 + r0 + tx] = f2bf(tile[tx][ty + i]);
        return;
    }
    // per-batch mask compaction scan -> ridx[b][pos] = original n (kept rows),
    // tail slots zero-filled so gathers are always in-bounds
    int b = bid - (NB_CVT + NB_TQKV + NB_TPROJ);
    int keep[8], lc = 0;
    #pragma unroll
    for (int u = 0; u < 8; ++u) {
        keep[u] = (mask[b * SEQ + tid * 8 + u] > 0) ? 0 : 1;
        lc += keep[u];
    }
    s[tid] = lc;
    __syncthreads();
    for (int d = 1; d < 256; d <<= 1) {
        int w = (tid >= d) ? s[tid - d] : 0;
        __syncthreads();
        s[tid] += w;
        __syncthreads();
    }
    int pos = s[tid] - lc;
    #pragma unroll
    for (int u = 0; u < 8; ++u) {
        if (keep[u]) ridx[b * SEQ + pos++] = tid * 8 + u;
    }
    int total = s[255];
    for (int i = total + tid; i < SEQ; i += 256)
        ridx[b * SEQ + i] = 0;
    if (tid == 255) cnt[b] = total;
}

// ---------------- GEMM 1 (merged): Q-path + KV-path in one dispatch -------
// y<8:  Q = xb @ Wqkvt[:1024], pre-scaled, -> [B,H,N,Dh]
// y>=8: K,V = gather(xb,ridx) @ Wqkvt[1024:], compacted M, -> Kc / Vct
// m97-proven structure: 128x128 tile, BK=64, 16B-granule XOR swizzle.
#define BK 64

__global__ __launch_bounds__(256, 2)
void gemm_qkv2_kernel(const unsigned short* __restrict__ A,
                      const unsigned short* __restrict__ Bt,
                      const int* __restrict__ ridx,
                      const int* __restrict__ cnt,
                      unsigned short* __restrict__ Q,
                      unsigned short* __restrict__ Kc,
                      unsigned short* __restrict__ Vct) {
    __shared__ __align__(16) unsigned short sA[128 * 64];
    __shared__ __align__(16) unsigned short sB[128 * 64];
    const int Kdim = 1024;
    int tid = threadIdx.x;
    int wave = tid >> 6, lane = tid & 63;
    int wm = (wave >> 1) * 64, wn = (wave & 1) * 64;
    int l15 = lane & 15, quad = lane >> 4;
    int lr = lane >> 3, lc8 = ((lane & 7) ^ lr) * 8;  // swizzled source col

    const bool qpath = (blockIdx.y < 8);
    int m0, n0, b = 0, kn = 0;
    const unsigned short* aPtr[4];   // per-lane A source base (col k0=0)

    if (qpath) {
        m0 = blockIdx.x * 128;
        n0 = blockIdx.y * 128;
        #pragma unroll
        for (int it = 0; it < 4; ++it) {
            int gr = (wave * 4 + it) * 8 + lr;
            aPtr[it] = A + (size_t)(m0 + gr) * Kdim + lc8;
        }
    } else {
        b  = blockIdx.x >> 4;
        m0 = (blockIdx.x & 15) * 128;
        kn = cnt[b];
        if (m0 >= kn) return;             // block-uniform, before any barrier
        n0 = 1024 + (blockIdx.y - 8) * 128;
        #pragma unroll
        for (int it = 0; it < 4; ++it) {
            int gr = (wave * 4 + it) * 8 + lr;
            int rid = ridx[b * SEQ + m0 + gr];    // original n (0 for tail)
            aPtr[it] = A + (size_t)(b * SEQ + rid) * Kdim + lc8;
        }
    }

    f32x4 acc[4][4] = {};

    for (int k0 = 0; k0 < Kdim; k0 += BK) {
        #pragma unroll
        for (int it = 0; it < 4; ++it) {
            int c = wave * 4 + it;            // chunk: 8 rows x 64 cols
            int gr = c * 8 + lr;
            g2l16(aPtr[it] + k0, &sA[c * 512]);
            g2l16(Bt + (size_t)(n0 + gr) * Kdim + k0 + lc8, &sB[c * 512]);
        }
        __syncthreads();
        #pragma unroll
        for (int kk = 0; kk < BK; kk += 32) {
            bf16x8 af[4], bfr[4];
            #pragma unroll
            for (int i = 0; i < 4; ++i) {
                int r = wm + i * 16 + l15;
                int q = ((kk >> 3) + quad) ^ (r & 7);
                af[i] = __builtin_bit_cast(bf16x8, *(const uint4a*)(&sA[r * 64 + q * 8]));
            }
            #pragma unroll
            for (int j = 0; j < 4; ++j) {
                int r = wn + j * 16 + l15;
                int q = ((kk >> 3) + quad) ^ (r & 7);
                bfr[j] = __builtin_bit_cast(bf16x8, *(const uint4a*)(&sB[r * 64 + q * 8]));
            }
            #pragma unroll
            for (int i = 0; i < 4; ++i)
                #pragma unroll
                for (int j = 0; j < 4; ++j)
                    acc[i][j] = __builtin_amdgcn_mfma_f32_16x16x32_bf16(af[i], bfr[j], acc[i][j], 0, 0, 0);
        }
        __syncthreads();
    }

    if (qpath) {
        // Q pre-scaled by C1SCALE -> [B,H,N,Dh]
        #pragma unroll
        for (int i = 0; i < 4; ++i) {
            #pragma unroll
            for (int j = 0; j < 4; ++j) {
                int col = n0 + wn + j * 16 + l15;
                int h = col >> 6;
                int d = col & 63;
                int row0 = m0 + wm + i * 16 + quad * 4;
                int bb = row0 >> 11, n = row0 & 2047;
                size_t bh = (size_t)(bb * NH + h);
                uint32_t p01 = pk2bf(acc[i][j][0] * C1SCALE, acc[i][j][1] * C1SCALE);
                uint32_t p23 = pk2bf(acc[i][j][2] * C1SCALE, acc[i][j][3] * C1SCALE);
                size_t base = (bh * SEQ + n) * HD + d;
                Q[base]          = (unsigned short)p01;
                Q[base + HD]     = (unsigned short)(p01 >> 16);
                Q[base + 2 * HD] = (unsigned short)p23;
                Q[base + 3 * HD] = (unsigned short)(p23 >> 16);
            }
        }
    } else {
        // rows already compacted positions; guard tail rows
        #pragma unroll
        for (int i = 0; i < 4; ++i) {
            #pragma unroll
            for (int j = 0; j < 4; ++j) {
                int c2 = (n0 - 1024) + wn + j * 16 + l15;   // 0..2047
                int three = c2 >> 10;                        // 0=K, 1=V
                int h = (c2 >> 6) & 15;
                int d = c2 & 63;
                int pf0 = m0 + wm + i * 16 + quad * 4;
                size_t bh = (size_t)(b * NH + h);
                if (three == 0) {
                    #pragma unroll
                    for (int r = 0; r < 4; ++r) {
                        int pf = pf0 + r;
                        if (pf < kn) Kc[(bh * SEQ + pf) * HD + d] = f2bf(acc[i][j][r]);
                    }
                } else {
                    #pragma unroll
                    for (int r = 0; r < 4; ++r) {
                        int pf = pf0 + r;
                        if (pf < kn) Vct[(bh * HD + d) * SEQ + pf] = f2bf(acc[i][j][r]);
                    }
                }
            }
        }
    }
}

// ---------------- GEMM 2: out = attn @ Wproj + bias (fp32 out) ------------
__global__ __launch_bounds__(256, 2)
void gemm_proj_kernel(const unsigned short* __restrict__ A,
                      const unsigned short* __restrict__ Bt,
                      const float* __restrict__ bias,
                      float* __restrict__ Out) {
    __shared__ __align__(16) unsigned short sA[128 * 64];
    __shared__ __align__(16) unsigned short sB[128 * 64];
    const int Kdim = 1024;
    int m0 = blockIdx.x * 128;
    int n0 = blockIdx.y * 128;
    int tid = threadIdx.x;
    int wave = tid >> 6, lane = tid & 63;
    int wm = (wave >> 1) * 64, wn = (wave & 1) * 64;
    int l15 = lane & 15, quad = lane >> 4;
    int lr = lane >> 3, lc8 = ((lane & 7) ^ lr) * 8;

    f32x4 acc[4][4] = {};

    for (int k0 = 0; k0 < Kdim; k0 += BK) {
        #pragma unroll
        for (int it = 0; it < 4; ++it) {
            int c = wave * 4 + it;
            int gr = c * 8 + lr;
            g2l16(A  + (size_t)(m0 + gr) * Kdim + k0 + lc8, &sA[c * 512]);
            g2l16(Bt + (size_t)(n0 + gr) * Kdim + k0 + lc8, &sB[c * 512]);
        }
        __syncthreads();
        #pragma unroll
        for (int kk = 0; kk < BK; kk += 32) {
            bf16x8 af[4], bfr[4];
            #pragma unroll
            for (int i = 0; i < 4; ++i) {
                int r = wm + i * 16 + l15;
                int q = ((kk >> 3) + quad) ^ (r & 7);
                af[i] = __builtin_bit_cast(bf16x8, *(const uint4a*)(&sA[r * 64 + q * 8]));
            }
            #pragma unroll
            for (int j = 0; j < 4; ++j) {
                int r = wn + j * 16 + l15;
                int q = ((kk >> 3) + quad) ^ (r & 7);
                bfr[j] = __builtin_bit_cast(bf16x8, *(const uint4a*)(&sB[r * 64 + q * 8]));
            }
            #pragma unroll
            for (int i = 0; i < 4; ++i)
                #pragma unroll
                for (int j = 0; j < 4; ++j)
                    acc[i][j] = __builtin_amdgcn_mfma_f32_16x16x32_bf16(af[i], bfr[j], acc[i][j], 0, 0, 0);
        }
        __syncthreads();
    }

    #pragma unroll
    for (int i = 0; i < 4; ++i) {
        #pragma unroll
        for (int j = 0; j < 4; ++j) {
            int col = n0 + wn + j * 16 + l15;
            float bv = bias[col];
            #pragma unroll
            for (int r = 0; r < 4; ++r) {
                int row = m0 + wm + i * 16 + quad * 4 + r;
                Out[(size_t)row * CDIM + col] = acc[i][j][r] + bv;
            }
        }
    }
}

// ---------------- Flash attention v12 --------------------------------------
// v11 (swapped QK^T, b64 P-writes) + conflict-free sP:
//   SPD 72 -> 64 (128B rows) with G4 XOR swizzle on 16B granules:
//   granule' = granule ^ (row & 7), applied identically on write (b64 stays
//   inside its granule) and read (b128 = one granule). Write banks land at
//   the b64 hardware minimum (4/bank); reads are 2-way (free, m136).
//   sP shrinks 18.4 KB -> 16 KB => LDS 32768 => 5 blocks/CU (was 4): +25%
//   resident waves to overlap the exp2 (trans), DS and MFMA pipes.
#define SPD 64   /* sP row stride (shorts), 128B rows, XOR-swizzled */

__global__ __launch_bounds__(256, 4)
void flash_attn_kernel(const unsigned short* __restrict__ Q,
                       const unsigned short* __restrict__ Kg,
                       const unsigned short* __restrict__ Vt,
                       const int* __restrict__ cnt,
                       unsigned short* __restrict__ O) {
    int bh = blockIdx.x;
    int q0 = blockIdx.y * 128;
    int b = bh >> 4, h = bh & 15;
    int tid = threadIdx.x;
    int wave = tid >> 6, lane = tid & 63;
    int l15 = lane & 15, quad = lane >> 4;
    int lr = lane >> 3, lc8 = ((lane & 7) ^ lr) * 8;

    const int kn = cnt[b];

    const size_t head_off = (size_t)bh * SEQ * HD;
    const unsigned short* Qh = Q + head_off;
    const unsigned short* Kh = Kg + head_off;
    const unsigned short* Vh = Vt + head_off;   // [HD][SEQ]

    __shared__ __align__(16) unsigned short sK [64 * 64];
    __shared__ __align__(16) unsigned short sVt[64 * 64];
    __shared__ __align__(16) unsigned short sP [4][32 * SPD];  // per-wave P [q][k], swizzled

    bf16x8 qf[2][2];
    #pragma unroll
    for (int mt = 0; mt < 2; ++mt) {
        const unsigned short* qp = Qh + (size_t)(q0 + wave * 32 + mt * 16 + l15) * HD + quad * 8;
        qf[mt][0] = __builtin_bit_cast(bf16x8, *(const uint4a*)(qp));
        qf[mt][1] = __builtin_bit_cast(bf16x8, *(const uint4a*)(qp + 32));
    }

    bf16x8 ones;
    {
        uint4 ov;
        ov.x = ov.y = ov.z = ov.w = 0x3F803F80u;
        ones = __builtin_bit_cast(bf16x8, ov);
    }

    f32x4 oacc[2][4] = {};
    f32x4 oextra[2] = {};   // oextra[mt][r] = l[row] (ones-column MFMA)

    for (int k0 = 0; k0 < kn; k0 += 64) {
        #pragma unroll
        for (int it = 0; it < 2; ++it) {
            int c = wave * 2 + it;
            int gr = c * 8 + lr;
            g2l16(Kh + (size_t)(k0 + gr) * HD + lc8, &sK[c * 512]);
            g2l16(Vh + (size_t)gr * SEQ + k0 + lc8, &sVt[c * 512]);
        }
        __syncthreads();

        bool tail = (k0 + 64 > kn);   // block-uniform

        // ---- S^T = K Q^T for BOTH mt halves; each kf pair read once ----
        // s[mt][j][r] = P[q = mt*16+l15][k = j*16 + quad*4 + r]  (pre-exp)
        f32x4 s[2][4] = {};
        #pragma unroll
        for (int j = 0; j < 4; ++j) {
            int r = j * 16 + l15, sw = r & 7;
            uint4 v0 = *(const uint4a*)(&sK[r * 64 + ((quad ^ sw) * 8)]);
            uint4 v1 = *(const uint4a*)(&sK[r * 64 + (((4 + quad) ^ sw) * 8)]);
            bf16x8 k0f = __builtin_bit_cast(bf16x8, v0);
            bf16x8 k1f = __builtin_bit_cast(bf16x8, v1);
            __builtin_amdgcn_s_setprio(1);
            s[0][j] = __builtin_amdgcn_mfma_f32_16x16x32_bf16(k0f, qf[0][0], s[0][j], 0, 0, 0);
            s[0][j] = __builtin_amdgcn_mfma_f32_16x16x32_bf16(k1f, qf[0][1], s[0][j], 0, 0, 0);
            s[1][j] = __builtin_amdgcn_mfma_f32_16x16x32_bf16(k0f, qf[1][0], s[1][j], 0, 0, 0);
            s[1][j] = __builtin_amdgcn_mfma_f32_16x16x32_bf16(k1f, qf[1][1], s[1][j], 0, 0, 0);
            __builtin_amdgcn_s_setprio(0);
        }

        // ---- softmax (exp2) + pack: one b64 write per (mt,j), swizzled ----
        unsigned short* sp = &sP[wave][0];
        #pragma unroll
        for (int mt = 0; mt < 2; ++mt) {
            int row = mt * 16 + l15;
            #pragma unroll
            for (int j = 0; j < 4; ++j) {
                if (tail) {
                    int kb = k0 + j * 16 + quad * 4;
                    #pragma unroll
                    for (int r = 0; r < 4; ++r)
                        s[mt][j][r] = __builtin_amdgcn_exp2f(s[mt][j][r] + ((kb + r < kn) ? 0.f : -1e30f));
                } else {
                    #pragma unroll
                    for (int r = 0; r < 4; ++r)
                        s[mt][j][r] = __builtin_amdgcn_exp2f(s[mt][j][r]);
                }
                uint2 wv;
                wv.x = pk2bf(s[mt][j][0], s[mt][j][1]);
                wv.y = pk2bf(s[mt][j][2], s[mt][j][3]);
                // logical granule g = 2j + (quad>>1); physical = g ^ (row&7)
                int g = (2 * j + (quad >> 1)) ^ (l15 & 7);
                *(uint2a*)(&sp[row * SPD + g * 8 + (quad & 1) * 4]) = wv;
            }
        }

        // ---- O += P V for BOTH mt halves; each vf read once ----
        #pragma unroll
        for (int kc = 0; kc < 2; ++kc) {
            // logical granule g = kc*4 + quad; physical = g ^ (row&7); rows
            // l15 and 16+l15 share the same key (l15&7)
            int gcol = ((kc * 4 + quad) ^ (l15 & 7)) * 8;
            uint4 a0 = *(const uint4a*)(&sp[(l15)      * SPD + gcol]);
            uint4 a1 = *(const uint4a*)(&sp[(16 + l15) * SPD + gcol]);
            bf16x8 af0 = __builtin_bit_cast(bf16x8, a0);
            bf16x8 af1 = __builtin_bit_cast(bf16x8, a1);
            __builtin_amdgcn_s_setprio(1);
            #pragma unroll
            for (int jd = 0; jd < 4; ++jd) {
                int r = jd * 16 + l15;
                int q = ((kc * 4 + quad) ^ (r & 7)) * 8;
                uint4 bv = *(const uint4a*)(&sVt[r * 64 + q]);
                bf16x8 vf = __builtin_bit_cast(bf16x8, bv);
                oacc[0][jd] = __builtin_amdgcn_mfma_f32_16x16x32_bf16(af0, vf, oacc[0][jd], 0, 0, 0);
                oacc[1][jd] = __builtin_amdgcn_mfma_f32_16x16x32_bf16(af1, vf, oacc[1][jd], 0, 0, 0);
            }
            oextra[0] = __builtin_amdgcn_mfma_f32_16x16x32_bf16(af0, ones, oextra[0], 0, 0, 0);
            oextra[1] = __builtin_amdgcn_mfma_f32_16x16x32_bf16(af1, ones, oextra[1], 0, 0, 0);
            __builtin_amdgcn_s_setprio(0);
        }
        __syncthreads();
    }

    // epilogue: O *= 1/l, write [B,N,C] bf16  (oacc/oextra layouts unchanged)
    #pragma unroll
    for (int mt = 0; mt < 2; ++mt) {
        float rl[4];
        #pragma unroll
        for (int r = 0; r < 4; ++r) rl[r] = __builtin_amdgcn_rcpf(oextra[mt][r]);
        #pragma unroll
        for (int jd = 0; jd < 4; ++jd) {
            int d = jd * 16 + l15;
            size_t base = ((size_t)(b * SEQ + q0 + wave * 32 + mt * 16 + quad * 4)) * CDIM + h * HD + d;
            uint32_t p01 = pk2bf(oacc[mt][jd][0] * rl[0], oacc[mt][jd][1] * rl[1]);
            uint32_t p23 = pk2bf(oacc[mt][jd][2] * rl[2], oacc[mt][jd][3] * rl[3]);
            O[base]            = (unsigned short)p01;
            O[base + CDIM]     = (unsigned short)(p01 >> 16);
            O[base + 2 * CDIM] = (unsigned short)p23;
            O[base + 3 * CDIM] = (unsigned short)(p23 >> 16);
        }
    }
}

extern "C" void kernel_launch(void* const* d_in, const int* in_sizes, int n_in,
                              void* d_out, int out_size, void* d_ws, size_t ws_size,
                              hipStream_t stream) {
    const float* x     = (const float*)d_in[0];
    const float* Wqkv  = (const float*)d_in[1];
    const float* Wproj = (const float*)d_in[2];
    const float* bproj = (const float*)d_in[3];
    const int*   mask  = (const int*)d_in[4];
    float* out = (float*)d_out;

    char* ws = (char*)d_ws;
    unsigned short* xb     = (unsigned short*)(ws);                       // 16 MB (also attn out)
    unsigned short* Wqkvt  = (unsigned short*)(ws + (16u << 20));         // 6 MB
    unsigned short* Wprojt = (unsigned short*)(ws + (22u << 20));         // 2 MB
    unsigned short* Qb     = (unsigned short*)(ws + (24u << 20));         // 16 MB
    unsigned short* Kb     = (unsigned short*)(ws + (40u << 20));         // 16 MB
    unsigned short* Vtb    = (unsigned short*)(ws + (56u << 20));         // 16 MB, ends 72 MB
    int*            ridx   = (int*)(ws + (72u << 20));                    // 32 KB
    int*            cntb   = (int*)(ws + (72u << 20) + (32u << 10));      // 16 B

    prep_kernel<<<dim3(NB_PREP), dim3(256), 0, stream>>>(x, Wqkv, Wproj, mask,
                                                         xb, Wqkvt, Wprojt, ridx, cntb);
    gemm_qkv2_kernel<<<dim3(64, 24), dim3(256), 0, stream>>>(xb, Wqkvt, ridx, cntb, Qb, Kb, Vtb);
    flash_attn_kernel<<<dim3(64, 16), dim3(256), 0, stream>>>(Qb, Kb, Vtb, cntb, xb);
    gemm_proj_kernel<<<dim3(64, 8), dim3(256), 0, stream>>>(xb, Wprojt, bproj, out);
}